// Round 4
// baseline (360.788 us; speedup 1.0000x reference)
//
#include <hip/hip_runtime.h>

// DenselyCnnAttLayer: B=64, S=512, L=6, D=512, fp32.
//
// R4 structure: ONE wave per TWO positions (software pipeline).
//  - Issue all 24 global_load_dwordx4 (24 KB/wave in flight), then process
//    pos0 while pos1's loads are still in flight, then process pos1.
//    Attacks the measured phase serialization: R0-R3 all showed ~3.3 TB/s
//    combined with VALUBusy <18% and occupancy >70% -- each wave blocked on
//    one vmcnt drain then ran a ~1-2k cy dependent chain issuing no memory.
//  - Plain stores: nt-store was an empirical ~10% regression (R0 125us
//    without it vs R1-R3 136-145us with it; only change that took effect).
//  - Remat/ordering guard: single asm volatile("" ::: "memory") after the
//    loads. Loads cannot sink below it, and re-loading past a memory
//    clobber is unsound so the 96 loaded floats cannot be rematerialized.
//    Unlike the old operand-pinning KEEP (R1-R3), it does NOT force a
//    vmcnt(0) drain, so pos0 math can start at vmcnt(12).
// R3 post-mortem: L3 is already capacity-optimal (FETCH 196.8 of 402.7 MB
// ~= (256MB - writes)/403), so traffic cannot be reduced; the only lever
// left is latency/phase overlap.
constexpr int Bc = 64, Sc = 512, Lc = 6, Dc = 512;

typedef float f32x4 __attribute__((ext_vector_type(4)));

__global__ __launch_bounds__(256) void densely_att_kernel(
    const float* __restrict__ x0, const float* __restrict__ x1,
    const float* __restrict__ x2, const float* __restrict__ x3,
    const float* __restrict__ x4, const float* __restrict__ x5,
    const float* __restrict__ Ws, float* __restrict__ out)
{
    const int wid  = threadIdx.x >> 6;     // 0..3
    const int lane = threadIdx.x & 63;

    // Wave handles positions pos0 = 2*w and pos0+1 (consecutive).
    const long pos0 = ((long)blockIdx.x * 4 + wid) * 2;

    const float* xs[Lc] = {x0, x1, x2, x3, x4, x5};

    // pos0 is even and Sc is even -> s never wraps within the pair.
    const int s0 = __builtin_amdgcn_readfirstlane((int)(pos0 % Sc));

    const size_t pa = (size_t)pos0 * Dc + (size_t)lane * 4;  // pos0 base
    const size_t pb = pa + Dc;                               // pos1 base

    // ---- Issue ALL 24 loads back-to-back: 24 KB in flight per wave.
    f32x4 v[2][Lc][2];
    #pragma unroll
    for (int j = 0; j < Lc; ++j) {
        v[0][j][0] = *(const f32x4*)(xs[j] + pa);
        v[0][j][1] = *(const f32x4*)(xs[j] + pa + 256);
    }
    #pragma unroll
    for (int j = 0; j < Lc; ++j) {
        v[1][j][0] = *(const f32x4*)(xs[j] + pb);
        v[1][j][1] = *(const f32x4*)(xs[j] + pb + 256);
    }
    // Compile-time barrier: no load sinks below this point, and loaded
    // values cannot be legally rematerialized after it. No vmcnt forced.
    asm volatile("" ::: "memory");

    // ---- Process the two positions in sequence (p is unrolled constant).
    #pragma unroll
    for (int p = 0; p < 2; ++p) {
        float ssum[Lc];
        #pragma unroll
        for (int j = 0; j < Lc; ++j) {
            f32x4 t = v[p][j][0] + v[p][j][1];
            ssum[j] = (t.x + t.y) + (t.z + t.w);
        }

        // Butterfly reduce across the 64-lane wave -> full sum over D.
        #pragma unroll
        for (int off = 32; off >= 1; off >>= 1) {
            #pragma unroll
            for (int j = 0; j < Lc; ++j)
                ssum[j] += __shfl_xor(ssum[j], off, 64);
        }

        // logits[m] = sum_l ssum[l] * Ws[s, l, m];  Ws is (S,L,L) row-major
        const float* __restrict__ w = Ws + (size_t)(s0 + p) * (Lc * Lc);
        float logits[Lc];
        #pragma unroll
        for (int m = 0; m < Lc; ++m) {
            float acc = 0.f;
            #pragma unroll
            for (int l = 0; l < Lc; ++l)
                acc = fmaf(ssum[l], w[l * Lc + m], acc);
            logits[m] = acc;
        }

        // softmax over L (6 values, cheap)
        float mx = logits[0];
        #pragma unroll
        for (int m = 1; m < Lc; ++m) mx = fmaxf(mx, logits[m]);
        float a[Lc];
        float denom = 0.f;
        #pragma unroll
        for (int m = 0; m < Lc; ++m) {
            a[m] = __expf(logits[m] - mx);
            denom += a[m];
        }
        const float inv = 1.f / denom;
        #pragma unroll
        for (int m = 0; m < Lc; ++m) a[m] *= inv;

        // out[d] = sum_j a[j] * x_j[d]  (x values live in VGPRs)
        f32x4 o0 = {0.f, 0.f, 0.f, 0.f};
        f32x4 o1 = {0.f, 0.f, 0.f, 0.f};
        #pragma unroll
        for (int j = 0; j < Lc; ++j) {
            o0 += a[j] * v[p][j][0];
            o1 += a[j] * v[p][j][1];
        }
        const size_t ob = p ? pb : pa;
        *(f32x4*)(out + ob)       = o0;   // plain store (nt reverted)
        *(f32x4*)(out + ob + 256) = o1;
    }
}

extern "C" void kernel_launch(void* const* d_in, const int* in_sizes, int n_in,
                              void* d_out, int out_size, void* d_ws, size_t ws_size,
                              hipStream_t stream) {
    const float* x0 = (const float*)d_in[0];
    const float* x1 = (const float*)d_in[1];
    const float* x2 = (const float*)d_in[2];
    const float* x3 = (const float*)d_in[3];
    const float* x4 = (const float*)d_in[4];
    const float* x5 = (const float*)d_in[5];
    const float* Ws = (const float*)d_in[6];
    float* out = (float*)d_out;

    const int positions = Bc * Sc;            // 32768
    const int blocks = positions / 8;         // 2 pos/wave * 4 waves/block
    densely_att_kernel<<<blocks, 256, 0, stream>>>(x0, x1, x2, x3, x4, x5, Ws, out);
}

// Round 5
// 360.704 us; speedup vs baseline: 1.0002x; 1.0002x over previous
//
#include <hip/hip_runtime.h>

// DenselyCnnAttLayer: B=64, S=512, L=6, D=512, fp32.
//
// R5 = R0's best-measured structure (125 us) + bijective XCD-aware block
// swizzle. Evidence so far (R0-R4): per-wave MLP (6/12/24 KB in flight),
// occupancy (80%/71%/35%), barrier removal, pipelining -- ALL produced the
// same ~3.0-3.2 TB/s READ-side rate. The m13 copy reference (6.29 TB/s
// r+w) has a 3.15 TB/s read side -> we sit at 95-102% of the only
// measured read-side number on this chip, under every structure. The wall
// is below the CUs. FETCH=196.8MB is the L3 random-replacement
// equilibrium (can't be ordered away); traffic is minimal (each byte read
// once). Remaining untested lever: per-XCD request-stream locality.
// Default dispatch round-robins consecutive blocks across 8 XCDs, so each
// XCD's L2 port sees 6 STRIDED (every-8th-2KB) read streams. The swizzle
// gives XCD k a contiguous slab (positions [k*4096,(k+1)*4096)), so each
// port sees 6 sequential streams. nwg=16384 % 8 == 0 -> simple bijective
// form is valid.
//
// Reverted to plain stores (nt-store cost ~5-10%, R1-R3) and the 2-wave/
// position split (R0 measured fastest; also halves wave-lifetime compute).
constexpr int Bc = 64, Sc = 512, Lc = 6, Dc = 512;

typedef float f32x4 __attribute__((ext_vector_type(4)));

__global__ __launch_bounds__(256) void densely_att_kernel(
    const float* __restrict__ x0, const float* __restrict__ x1,
    const float* __restrict__ x2, const float* __restrict__ x3,
    const float* __restrict__ x4, const float* __restrict__ x5,
    const float* __restrict__ Ws, float* __restrict__ out)
{
    const int wave = threadIdx.x >> 6;     // 0..3
    const int lane = threadIdx.x & 63;
    const int pair = wave >> 1;            // 0..1 : which position in this block
    const int half = wave & 1;             // 0..1 : which half of D

    // Bijective XCD swizzle: XCD k (k = bid%8) owns the contiguous slab of
    // blocks [k*2048, (k+1)*2048) -> contiguous 1/8 of all positions.
    const int bid = (int)blockIdx.x;
    const int swz = (bid & 7) * 2048 + (bid >> 3);   // nwg = 16384

    const long pos = (long)swz * 2 + pair;           // b*S + s
    const int s_idx = __builtin_amdgcn_readfirstlane((int)(pos % Sc));

    const float* xs[Lc] = {x0, x1, x2, x3, x4, x5};

    // Each lane covers d = half*256 + lane*4 .. +3  (one float4 per array)
    const size_t base = (size_t)pos * Dc + (size_t)half * 256 + (size_t)lane * 4;

    // Issue all six loads; memory clobber forbids sinking below this point
    // and makes rematerialization (re-loading) illegal. No vmcnt forced.
    f32x4 v[Lc];
    #pragma unroll
    for (int j = 0; j < Lc; ++j)
        v[j] = *(const f32x4*)(xs[j] + base);
    asm volatile("" ::: "memory");

    float ssum[Lc];
    #pragma unroll
    for (int j = 0; j < Lc; ++j)
        ssum[j] = (v[j].x + v[j].y) + (v[j].z + v[j].w);

    // Butterfly reduce across the 64-lane wave -> sum over this half of D.
    #pragma unroll
    for (int off = 32; off >= 1; off >>= 1) {
        #pragma unroll
        for (int j = 0; j < Lc; ++j)
            ssum[j] += __shfl_xor(ssum[j], off, 64);
    }

    // Combine the two half-sums through LDS (24 B per position).
    __shared__ float sums[2][2][Lc];
    if (lane == 0) {
        #pragma unroll
        for (int j = 0; j < Lc; ++j) sums[pair][half][j] = ssum[j];
    }
    __syncthreads();
    #pragma unroll
    for (int j = 0; j < Lc; ++j)
        ssum[j] = sums[pair][0][j] + sums[pair][1][j];

    // logits[m] = sum_l ssum[l] * Ws[s, l, m];  Ws is (S, L, L) row-major
    const float* __restrict__ w = Ws + (size_t)s_idx * (Lc * Lc);
    float logits[Lc];
    #pragma unroll
    for (int m = 0; m < Lc; ++m) {
        float acc = 0.f;
        #pragma unroll
        for (int l = 0; l < Lc; ++l)
            acc = fmaf(ssum[l], w[l * Lc + m], acc);
        logits[m] = acc;
    }

    // softmax over L (redundant per lane; 6 values, cheap)
    float mx = logits[0];
    #pragma unroll
    for (int m = 1; m < Lc; ++m) mx = fmaxf(mx, logits[m]);
    float a[Lc];
    float denom = 0.f;
    #pragma unroll
    for (int m = 0; m < Lc; ++m) {
        a[m] = __expf(logits[m] - mx);
        denom += a[m];
    }
    const float inv = 1.f / denom;
    #pragma unroll
    for (int m = 0; m < Lc; ++m) a[m] *= inv;

    // out[d] = sum_j a[j] * x_j[d]  (x values still live in VGPRs)
    f32x4 o = {0.f, 0.f, 0.f, 0.f};
    #pragma unroll
    for (int j = 0; j < Lc; ++j)
        o += a[j] * v[j];
    *(f32x4*)(out + base) = o;   // plain store (nt hurt 5-10%, R1-R3)
}

extern "C" void kernel_launch(void* const* d_in, const int* in_sizes, int n_in,
                              void* d_out, int out_size, void* d_ws, size_t ws_size,
                              hipStream_t stream) {
    const float* x0 = (const float*)d_in[0];
    const float* x1 = (const float*)d_in[1];
    const float* x2 = (const float*)d_in[2];
    const float* x3 = (const float*)d_in[3];
    const float* x4 = (const float*)d_in[4];
    const float* x5 = (const float*)d_in[5];
    const float* Ws = (const float*)d_in[6];
    float* out = (float*)d_out;

    const int positions = Bc * Sc;            // 32768
    const int blocks = positions / 2;         // 16384; % 8 == 0 (swizzle valid)
    densely_att_kernel<<<blocks, 256, 0, stream>>>(x0, x1, x2, x3, x4, x5, Ws, out);
}

// Round 6
// 336.497 us; speedup vs baseline: 1.0722x; 1.0719x over previous
//
#include <hip/hip_runtime.h>

// DenselyCnnAttLayer: B=64, S=512, L=6, D=512, fp32.
//
// R6: L3-tier experiment. R0-R5 established that NO CU-side lever moves
// the ~3.0 TB/s read-side delivery rate: per-wave MLP (6/12/24 KB in
// flight), occupancy (80/71/35%), barrier removal, software pipelining,
// nt-store, XCD swizzle -- all null. Decomposing delivery by source:
//   HBM: 197 MB read at 2.0 TB/s total (25% of peak -- slack)
//   L3 : 206 MB at ~1.55 TB/s ... and 206MB/1.55 = 133 us = dispatch time.
// Model: effective L3-HIT service bandwidth for this 7-stream pattern is
// ~1.5-1.7 TB/s and is the binding constraint; the 51% random-replacement
// hit equilibrium routes half the traffic to the SLOW tier while HBM
// idles. Fix under test: non-temporal loads on all six x arrays -> lines
// not retained -> steady-state L3 hits ~0 -> all 403 MB served by HBM.
// Verification gate: FETCH_SIZE must rise 197 -> ~400 MB, else the hint
// didn't take and the timing is uninterpretable.
//   Case A (model right):  ~90-105 us, hbm_gbps ~4+ TB/s.
//   Case B (global ~3TB/s read cap): unchanged time, FETCH doubled ->
//          roofline established (all tiers saturate the same path).
//   Case C (HBM read-side weak): slower -> revert; equilibrium was optimal.
// Ws stays cached (hot, tiny). Store stays plain (nt-store was a
// regression R1-R3). No XCD swizzle (null, R5).
constexpr int Bc = 64, Sc = 512, Lc = 6, Dc = 512;

typedef float f32x4 __attribute__((ext_vector_type(4)));

__global__ __launch_bounds__(256) void densely_att_kernel(
    const float* __restrict__ x0, const float* __restrict__ x1,
    const float* __restrict__ x2, const float* __restrict__ x3,
    const float* __restrict__ x4, const float* __restrict__ x5,
    const float* __restrict__ Ws, float* __restrict__ out)
{
    const int wave = threadIdx.x >> 6;     // 0..3
    const int lane = threadIdx.x & 63;
    const int pair = wave >> 1;            // 0..1 : which position in this block
    const int half = wave & 1;             // 0..1 : which half of D

    const long pos = (long)blockIdx.x * 2 + pair;        // b*S + s
    const int s_idx = __builtin_amdgcn_readfirstlane((int)(pos % Sc));

    const float* xs[Lc] = {x0, x1, x2, x3, x4, x5};

    // Each lane covers d = half*256 + lane*4 .. +3  (one float4 per array)
    const size_t base = (size_t)pos * Dc + (size_t)half * 256 + (size_t)lane * 4;

    // Non-temporal loads: bypass L3 retention. Memory clobber afterwards
    // forbids sinking/remat; does not force a vmcnt drain.
    f32x4 v[Lc];
    #pragma unroll
    for (int j = 0; j < Lc; ++j)
        v[j] = __builtin_nontemporal_load((const f32x4*)(xs[j] + base));
    asm volatile("" ::: "memory");

    float ssum[Lc];
    #pragma unroll
    for (int j = 0; j < Lc; ++j)
        ssum[j] = (v[j].x + v[j].y) + (v[j].z + v[j].w);

    // Butterfly reduce across the 64-lane wave -> sum over this half of D.
    #pragma unroll
    for (int off = 32; off >= 1; off >>= 1) {
        #pragma unroll
        for (int j = 0; j < Lc; ++j)
            ssum[j] += __shfl_xor(ssum[j], off, 64);
    }

    // Combine the two half-sums through LDS (24 B per position).
    __shared__ float sums[2][2][Lc];
    if (lane == 0) {
        #pragma unroll
        for (int j = 0; j < Lc; ++j) sums[pair][half][j] = ssum[j];
    }
    __syncthreads();
    #pragma unroll
    for (int j = 0; j < Lc; ++j)
        ssum[j] = sums[pair][0][j] + sums[pair][1][j];

    // logits[m] = sum_l ssum[l] * Ws[s, l, m];  Ws is (S, L, L) row-major
    const float* __restrict__ w = Ws + (size_t)s_idx * (Lc * Lc);
    float logits[Lc];
    #pragma unroll
    for (int m = 0; m < Lc; ++m) {
        float acc = 0.f;
        #pragma unroll
        for (int l = 0; l < Lc; ++l)
            acc = fmaf(ssum[l], w[l * Lc + m], acc);
        logits[m] = acc;
    }

    // softmax over L (redundant per lane; 6 values, cheap)
    float mx = logits[0];
    #pragma unroll
    for (int m = 1; m < Lc; ++m) mx = fmaxf(mx, logits[m]);
    float a[Lc];
    float denom = 0.f;
    #pragma unroll
    for (int m = 0; m < Lc; ++m) {
        a[m] = __expf(logits[m] - mx);
        denom += a[m];
    }
    const float inv = 1.f / denom;
    #pragma unroll
    for (int m = 0; m < Lc; ++m) a[m] *= inv;

    // out[d] = sum_j a[j] * x_j[d]  (x values still live in VGPRs)
    f32x4 o = {0.f, 0.f, 0.f, 0.f};
    #pragma unroll
    for (int j = 0; j < Lc; ++j)
        o += a[j] * v[j];
    *(f32x4*)(out + base) = o;   // plain store

}

extern "C" void kernel_launch(void* const* d_in, const int* in_sizes, int n_in,
                              void* d_out, int out_size, void* d_ws, size_t ws_size,
                              hipStream_t stream) {
    const float* x0 = (const float*)d_in[0];
    const float* x1 = (const float*)d_in[1];
    const float* x2 = (const float*)d_in[2];
    const float* x3 = (const float*)d_in[3];
    const float* x4 = (const float*)d_in[4];
    const float* x5 = (const float*)d_in[5];
    const float* Ws = (const float*)d_in[6];
    float* out = (float*)d_out;

    const int positions = Bc * Sc;            // 32768
    const int blocks = positions / 2;         // 2 positions (4 waves) per block
    densely_att_kernel<<<blocks, 256, 0, stream>>>(x0, x1, x2, x3, x4, x5, Ws, out);
}